// Round 21
// baseline (148.294 us; speedup 1.0000x reference)
//
#include <hip/hip_runtime.h>
#include <hip/hip_bf16.h>

// Problem constants
#define BB 2
#define SS 2048
#define DM 1024
#define KVD 512
#define NH 8
#define NQ 2
#define QH 16
#define DH 64
#define MROWS 4096   // B*S

typedef float f32x4 __attribute__((ext_vector_type(4)));
typedef short short8 __attribute__((ext_vector_type(8)));
typedef short short4v __attribute__((ext_vector_type(4)));
typedef unsigned uint2v __attribute__((ext_vector_type(2)));

__device__ __forceinline__ float elu_f(float x) {
    return x > 0.0f ? x : (__expf(x) - 1.0f);
}

// float -> bf16 (round to nearest even), raw short
__device__ __forceinline__ short f2bf(float f) {
    union { float f; unsigned u; } v; v.f = f;
    unsigned r = v.u + 0x7FFFu + ((v.u >> 16) & 1u);
    return (short)(r >> 16);
}
__device__ __forceinline__ float bf2f(short s) {
    union { unsigned u; float f; } v;
    v.u = ((unsigned)(unsigned short)s) << 16;
    return v.f;
}
// packed f32x2 -> bf16x2 (hardware cvt)
__device__ __forceinline__ unsigned cvtpk(float lo, float hi) {
    unsigned u;
    asm("v_cvt_pk_bf16_f32 %0, %1, %2" : "=v"(u) : "v"(lo), "v"(hi));
    return u;
}

// XOR-swizzled LDS index (in shorts) for 128B rows: bijective 16B-slot permute.
__device__ __forceinline__ int swzs(int row, int byteoff) {
    return (row * 128 + (byteoff ^ ((row & 7) << 4))) >> 1;
}

// global -> LDS direct DMA, 16B per lane. LDS dest linear; source pre-swizzled.
#define GLD16(gp, lp) __builtin_amdgcn_global_load_lds( \
    (const __attribute__((address_space(1))) void*)(gp), \
    (__attribute__((address_space(3))) void*)(lp), 16, 0, 0)

// ---------------------------------------------------------------------------
// 128-row x 64-col staging (256 thr): LDS[r][s] = G[r][s ^ (r&7)]
// ---------------------------------------------------------------------------
__device__ __forceinline__ void stage_gl(const short* __restrict__ src, int ld,
                                         int row0, int k0, short* L,
                                         int wv, int lane) {
    const int srow = lane >> 3, sslot = lane & 7;
    #pragma unroll
    for (int i = 0; i < 4; i++) {
        int row = wv * 32 + i * 8 + srow;
        int slot = sslot ^ (row & 7);
        GLD16(&src[(size_t)(row0 + row) * ld + k0 + slot * 8],
              &L[(wv * 32 + i * 8) * 64]);
    }
}

// 64-row x 64-col staging (256 thr = 4 waves, 2 GLD16 each)
__device__ __forceinline__ void stage_gl64(const short* __restrict__ src, int ld,
                                           int row0, int k0, short* L,
                                           int wv, int lane) {
    const int srow = lane >> 3, sslot = lane & 7;
    #pragma unroll
    for (int i = 0; i < 2; i++) {
        int row = wv * 16 + i * 8 + srow;
        int slot = sslot ^ (row & 7);
        GLD16(&src[(size_t)(row0 + row) * ld + k0 + slot * 8],
              &L[(wv * 16 + i * 8) * 64]);
    }
}

__device__ __forceinline__ void mma_tile(const short* __restrict__ Als,
                                         const short* __restrict__ Bls,
                                         int mb, int nb, int qr, int kg,
                                         f32x4 acc[4][4]) {
    #pragma unroll
    for (int kc = 0; kc < 2; kc++) {
        short8 af[4], bg[4];
        #pragma unroll
        for (int mi = 0; mi < 4; mi++)
            af[mi] = *(const short8*)&Als[swzs(mb + mi * 16 + qr, kc * 64 + kg * 16)];
        #pragma unroll
        for (int ni = 0; ni < 4; ni++)
            bg[ni] = *(const short8*)&Bls[swzs(nb + ni * 16 + qr, kc * 64 + kg * 16)];
        #pragma unroll
        for (int mi = 0; mi < 4; mi++)
            #pragma unroll
            for (int ni = 0; ni < 4; ni++)
                acc[mi][ni] = __builtin_amdgcn_mfma_f32_16x16x32_bf16(
                    af[mi], bg[ni], acc[mi][ni], 0, 0, 0);
    }
}

// 64x64 tile: 4 waves in 2x2 grid, each 32x32 (2x2 fragments)
__device__ __forceinline__ void mma_tile64(const short* __restrict__ Als,
                                           const short* __restrict__ Bls,
                                           int mb, int nb, int qr, int kg,
                                           f32x4 acc[2][2]) {
    #pragma unroll
    for (int kc = 0; kc < 2; kc++) {
        short8 af[2], bg[2];
        #pragma unroll
        for (int mi = 0; mi < 2; mi++)
            af[mi] = *(const short8*)&Als[swzs(mb + mi * 16 + qr, kc * 64 + kg * 16)];
        #pragma unroll
        for (int ni = 0; ni < 2; ni++)
            bg[ni] = *(const short8*)&Bls[swzs(nb + ni * 16 + qr, kc * 64 + kg * 16)];
        #pragma unroll
        for (int mi = 0; mi < 2; mi++)
            #pragma unroll
            for (int ni = 0; ni < 2; ni++)
                acc[mi][ni] = __builtin_amdgcn_mfma_f32_16x16x32_bf16(
                    af[mi], bg[ni], acc[mi][ni], 0, 0, 0);
    }
}

// ---------------------------------------------------------------------------
// Fused prep: [0,2048) convert_x | [2048,2560) transpose_w | [2560,2624) mem
//             [2624,2880) out_mem = memory (delta GEMM accumulates via atomics)
// ---------------------------------------------------------------------------
__global__ __launch_bounds__(256) void prep_all(
        const float* __restrict__ x, const float* __restrict__ Wq,
        const float* __restrict__ Wk, const float* __restrict__ Wv,
        const float* __restrict__ memory,
        short* __restrict__ xb, short* __restrict__ wtb,
        short* __restrict__ memtb, float* __restrict__ out_mem) {
    __shared__ float Ts[64][65];
    const int blk = blockIdx.x;
    const int tid = threadIdx.x;

    if (blk < 2048) {                      // convert x -> bf16
        int i = (blk * 256 + tid) * 8;
        float4 a = *(const float4*)&x[i];
        float4 b = *(const float4*)&x[i + 4];
        short8 s;
        s[0] = f2bf(a.x); s[1] = f2bf(a.y); s[2] = f2bf(a.z); s[3] = f2bf(a.w);
        s[4] = f2bf(b.x); s[5] = f2bf(b.y); s[6] = f2bf(b.z); s[7] = f2bf(b.w);
        *(short8*)&xb[i] = s;
        return;
    }
    if (blk < 2560) {                      // Wt[n][k] = W[k][n] (fused q|k|v)
        int idx = blk - 2048;
        const int k0 = (idx & 15) * 64, n0 = (idx >> 4) * 64;
        const float* W; int ld, c0;
        if (n0 < 1024)      { W = Wq; ld = 1024; c0 = n0; }
        else if (n0 < 1536) { W = Wk; ld = 512;  c0 = n0 - 1024; }
        else                { W = Wv; ld = 512;  c0 = n0 - 1536; }
        #pragma unroll
        for (int i = 0; i < 16; i++) {
            int e = tid + 256 * i;
            int kk = e >> 6, nn = e & 63;
            Ts[nn][kk] = W[(size_t)(k0 + kk) * ld + c0 + nn];
        }
        __syncthreads();
        #pragma unroll
        for (int i = 0; i < 16; i++) {
            int e = tid + 256 * i;
            int nn = e >> 6, kk = e & 63;
            wtb[(size_t)(n0 + nn) * 1024 + k0 + kk] = f2bf(Ts[nn][kk]);
        }
        return;
    }
    if (blk < 2624) {                      // memT[n][k] = memory[k][n]
        int idx = blk - 2560;
        const int k0 = (idx & 7) * 64, n0 = (idx >> 3) * 64;
        #pragma unroll
        for (int i = 0; i < 16; i++) {
            int e = tid + 256 * i;
            int kk = e >> 6, nn = e & 63;
            Ts[nn][kk] = memory[(size_t)(k0 + kk) * 512 + n0 + nn];
        }
        __syncthreads();
        #pragma unroll
        for (int i = 0; i < 16; i++) {
            int e = tid + 256 * i;
            int nn = e >> 6, kk = e & 63;
            memtb[(size_t)(n0 + nn) * 512 + k0 + kk] = f2bf(Ts[nn][kk]);
        }
        return;
    }
    {                                      // out_mem = memory (float4)
        int idx = blk - 2624;              // 0..255
        int i = (idx * 256 + tid) * 4;
        *(float4*)&out_mem[i] = *(const float4*)&memory[i];
    }
}

// ---------------------------------------------------------------------------
// GEMM 1: QKV, 128x128 tiles, single-barrier double-buffered K-loop.
// Q -> qb,qelu ; K -> kbuf,kelu,keluT ; V -> vbuf,vt
// Tls ALIASES buffers (dead after K-loop; explicit barrier before reuse).
// ---------------------------------------------------------------------------
__global__ __launch_bounds__(256) void gemm_qkv_mfma(
        const short* __restrict__ xb, const short* __restrict__ wtb,
        short* __restrict__ q, short* __restrict__ k, short* __restrict__ v,
        short* __restrict__ qelu, short* __restrict__ kelu,
        short* __restrict__ keluT, short* __restrict__ vt) {
    __shared__ __align__(16) short SMEM[32768];   // A0 B0 A1 B1 (4x8192); Tls aliases
    short (*Tls)[130] = (short(*)[130])SMEM;
    const int n0 = blockIdx.x * 128, m0 = blockIdx.y * 128;
    const int tid = threadIdx.x, lane = tid & 63, wv = tid >> 6;
    const int qr = lane & 15, kg = lane >> 4;
    const int mb = (wv >> 1) * 64, nb = (wv & 1) * 64;

    f32x4 acc[4][4];
    #pragma unroll
    for (int i = 0; i < 4; i++)
        #pragma unroll
        for (int j = 0; j < 4; j++) acc[i][j] = (f32x4){0.f, 0.f, 0.f, 0.f};

    // prologue: stage tile 0 into buffer set 0
    stage_gl(xb, 1024, m0, 0, SMEM, wv, lane);
    stage_gl(wtb, 1024, n0, 0, SMEM + 8192, wv, lane);

    for (int kt = 0; kt < 16; kt++) {
        const int cur = kt & 1;
        short* Acur = SMEM + cur * 16384;
        short* Bcur = Acur + 8192;
        __syncthreads();               // drains DMA for tile kt
        if (kt + 1 < 16) {
            short* Anxt = SMEM + (cur ^ 1) * 16384;
            stage_gl(xb, 1024, m0, (kt + 1) * 64, Anxt, wv, lane);
            stage_gl(wtb, 1024, n0, (kt + 1) * 64, Anxt + 8192, wv, lane);
        }
        mma_tile(Acur, Bcur, mb, nb, qr, kg, acc);
    }
    __syncthreads();   // all waves done with buffers before Tls overwrite

    const int kind = (n0 < 1024) ? 0 : (n0 < 1536) ? 1 : 2;
    #pragma unroll
    for (int mi = 0; mi < 4; mi++)
        #pragma unroll
        for (int ni = 0; ni < 4; ni++)
            #pragma unroll
            for (int r = 0; r < 4; r++) {
                int lr = mb + mi * 16 + kg * 4 + r;
                int lc = nb + ni * 16 + qr;
                int gr = m0 + lr;
                short val = f2bf(acc[mi][ni][r]);
                if (kind == 0) {
                    int gc = n0 + lc;
                    q[(size_t)gr * 1024 + gc] = val;
                    qelu[(size_t)gr * 1024 + gc] = f2bf(elu_f(bf2f(val)));
                } else if (kind == 1) {
                    int gc = (n0 - 1024) + lc;
                    k[(size_t)gr * 512 + gc] = val;
                    short ev = f2bf(elu_f(bf2f(val)));
                    kelu[(size_t)gr * 512 + gc] = ev;
                    Tls[lr][lc] = ev;
                } else {
                    int gc = (n0 - 1536) + lc;
                    v[(size_t)gr * 512 + gc] = val;
                    Tls[lr][lc] = val;
                }
            }

    if (kind == 0) return;
    __syncthreads();
    // transposed coalesced writes: out-row = local col, 128 contiguous elems
    const int lane16 = tid & 15, rgrp = tid >> 4;   // 16 row-groups of 16 lanes
    #pragma unroll
    for (int p = 0; p < 8; p++) {
        int lc2 = p * 16 + rgrp;
        short8 s;
        #pragma unroll
        for (int e = 0; e < 8; e++) s[e] = Tls[lane16 * 8 + e][lc2];
        if (kind == 1) {
            int gcT = (n0 - 1024) + lc2;
            *(short8*)&keluT[(size_t)gcT * 4096 + m0 + lane16 * 8] = s;
        } else {
            int gc = (n0 - 1536) + lc2;
            int bh2 = (m0 >> 11) * 8 + (gc >> 6);
            *(short8*)&vt[((size_t)bh2 * 64 + (gc & 63)) * SS + (m0 & 2047)
                          + lane16 * 8] = s;
        }
    }
}

// ---------------------------------------------------------------------------
// dens (blocks 0..3071: 12288 rows) + colsum of keluT (blocks 3072..3199)
// ---------------------------------------------------------------------------
__global__ __launch_bounds__(256) void den_colsum(
        const short* __restrict__ qelu, const short* __restrict__ kelu,
        const short* __restrict__ keluT, const float* __restrict__ norm,
        float* __restrict__ den_q, float* __restrict__ den_k,
        float* __restrict__ out_norm) {
    const int wavei = threadIdx.x >> 6, lane = threadIdx.x & 63;
    const int blk = blockIdx.x;
    if (blk < 3072) {
        const int row = blk * 4 + wavei;    // 12288 rows
        const short* src; float* den;
        if (row < 8192) { src = qelu + (size_t)row * 512; den = den_q + row; }
        else { int rk = row - 8192; src = kelu + (size_t)rk * 512; den = den_k + rk; }
        short8 vv = *(const short8*)&src[lane * 8];
        float4 n0 = *(const float4*)&norm[lane * 8];
        float4 n1 = *(const float4*)&norm[lane * 8 + 4];
        float nn[8] = {n0.x, n0.y, n0.z, n0.w, n1.x, n1.y, n1.z, n1.w};
        float s = 0.0f;
        #pragma unroll
        for (int j = 0; j < 8; j++) s += bf2f(vv[j]) * nn[j];
        #pragma unroll
        for (int off = 32; off >= 1; off >>= 1) s += __shfl_xor(s, off);
        if (lane == 0) *den = s;
    } else {
        const int row = (blk - 3072) * 4 + wavei;   // 512 rows of keluT
        float s = 0.0f;
        #pragma unroll
        for (int j = 0; j < 8; j++) {
            short8 vv = *(const short8*)&keluT[(size_t)row * 4096 + j * 512 + lane * 8];
            #pragma unroll
            for (int e = 0; e < 8; e++) s += bf2f(vv[e]);
        }
        #pragma unroll
        for (int off = 32; off >= 1; off >>= 1) s += __shfl_xor(s, off);
        if (lane == 0) out_norm[row] = norm[row] + s;
    }
}

// ---------------------------------------------------------------------------
// GEMM 2 (64x64, dbuf single-barrier): a_mem + blend -> out.
// Epilogue inputs (adotb, den_q, mw) PREFETCHED before the K-loop so their
// latency hides under the GEMM (loads stay in flight; uses are in epilogue).
// ---------------------------------------------------------------------------
__global__ __launch_bounds__(256) void gemm_amem_mfma(
        const short* __restrict__ qelu, const short* __restrict__ memtb,
        const short* __restrict__ adotb, const float* __restrict__ den_q,
        const float* __restrict__ mw, float* __restrict__ out) {
    __shared__ __align__(16) short SMEM[16384];   // A0 B0 A1 B1 (4x4096)
    const int n0 = blockIdx.x * 64, m0 = blockIdx.y * 64;
    const int tid = threadIdx.x, lane = tid & 63, wv = tid >> 6;
    const int qr = lane & 15, kg = lane >> 4;
    const int mb = (wv >> 1) * 32, nb = (wv & 1) * 32;

    // ---- epilogue-operand prefetch (T14-lite) ----
    const float mw0 = mw[0];
    float adv[2][2][4], dq[2][4];
    #pragma unroll
    for (int mi = 0; mi < 2; mi++) {
        int gr0 = m0 + mb + mi * 16 + kg * 4;
        #pragma unroll
        for (int r = 0; r < 4; r++) dq[mi][r] = den_q[gr0 + r];
        #pragma unroll
        for (int ni = 0; ni < 2; ni++) {
            int gc = n0 + nb + ni * 16 + qr;
            #pragma unroll
            for (int r = 0; r < 4; r++)
                adv[mi][ni][r] = bf2f(adotb[(size_t)(gr0 + r) * 512 + gc]);
        }
    }

    f32x4 acc[2][2];
    #pragma unroll
    for (int i = 0; i < 2; i++)
        #pragma unroll
        for (int j = 0; j < 2; j++) acc[i][j] = (f32x4){0.f, 0.f, 0.f, 0.f};

    stage_gl64(qelu, 512, m0, 0, SMEM, wv, lane);
    stage_gl64(memtb, 512, n0, 0, SMEM + 4096, wv, lane);
    for (int kt = 0; kt < 8; kt++) {
        const int cur = kt & 1;
        short* Acur = SMEM + cur * 8192;
        short* Bcur = Acur + 4096;
        __syncthreads();
        if (kt + 1 < 8) {
            short* Anxt = SMEM + (cur ^ 1) * 8192;
            stage_gl64(qelu, 512, m0, (kt + 1) * 64, Anxt, wv, lane);
            stage_gl64(memtb, 512, n0, (kt + 1) * 64, Anxt + 4096, wv, lane);
        }
        mma_tile64(Acur, Bcur, mb, nb, qr, kg, acc);
    }

    const float wgt = 1.0f / (1.0f + __expf(-mw0));
    #pragma unroll
    for (int mi = 0; mi < 2; mi++) {
        int gr0 = m0 + mb + mi * 16 + kg * 4;
        float invd[4];
        #pragma unroll
        for (int r = 0; r < 4; r++) invd[r] = wgt / dq[mi][r];
        #pragma unroll
        for (int ni = 0; ni < 2; ni++) {
            int gc = n0 + nb + ni * 16 + qr;
            #pragma unroll
            for (int r = 0; r < 4; r++) {
                size_t fo = (size_t)(gr0 + r) * 512 + gc;
                out[fo] = adv[mi][ni][r] * (1.0f - wgt)
                        + acc[mi][ni][r] * invd[r];
            }
        }
    }
}

// ---------------------------------------------------------------------------
// GEMM 3 (64x64, dbuf single-barrier): u = v - (kelu@memory)/den_k -> uT bf16.
// Epilogue inputs (vb, den_k) PREFETCHED before the K-loop.
// ---------------------------------------------------------------------------
__global__ __launch_bounds__(256) void gemm_u_mfma(
        const short* __restrict__ kelu, const short* __restrict__ memtb,
        const short* __restrict__ vb, const float* __restrict__ den_k,
        short* __restrict__ uT) {
    __shared__ __align__(16) short SMEM[16384];
    const int n0 = blockIdx.x * 64, m0 = blockIdx.y * 64;
    const int tid = threadIdx.x, lane = tid & 63, wv = tid >> 6;
    const int qr = lane & 15, kg = lane >> 4;
    const int mb = (wv >> 1) * 32, nb = (wv & 1) * 32;

    // ---- epilogue-operand prefetch (T14-lite) ----
    float vvp[2][2][4], dk[2][4];
    #pragma unroll
    for (int mi = 0; mi < 2; mi++) {
        int gr0 = m0 + mb + mi * 16 + kg * 4;
        #pragma unroll
        for (int r = 0; r < 4; r++) dk[mi][r] = den_k[gr0 + r];
        #pragma unroll
        for (int ni = 0; ni < 2; ni++) {
            int gc = n0 + nb + ni * 16 + qr;
            #pragma unroll
            for (int r = 0; r < 4; r++)
                vvp[mi][ni][r] = bf2f(vb[(size_t)(gr0 + r) * 512 + gc]);
        }
    }

    f32x4 acc[2][2];
    #pragma unroll
    for (int i = 0; i < 2; i++)
        #pragma unroll
        for (int j = 0; j < 2; j++) acc[i][j] = (f32x4){0.f, 0.f, 0.f, 0.f};

    stage_gl64(kelu, 512, m0, 0, SMEM, wv, lane);
    stage_gl64(memtb, 512, n0, 0, SMEM + 4096, wv, lane);
    for (int kt = 0; kt < 8; kt++) {
        const int cur = kt & 1;
        short* Acur = SMEM + cur * 8192;
        short* Bcur = Acur + 4096;
        __syncthreads();
        if (kt + 1 < 8) {
            short* Anxt = SMEM + (cur ^ 1) * 8192;
            stage_gl64(kelu, 512, m0, (kt + 1) * 64, Anxt, wv, lane);
            stage_gl64(memtb, 512, n0, (kt + 1) * 64, Anxt + 4096, wv, lane);
        }
        mma_tile64(Acur, Bcur, mb, nb, qr, kg, acc);
    }

    #pragma unroll
    for (int mi = 0; mi < 2; mi++) {
        int gr0 = m0 + mb + mi * 16 + kg * 4;
        float invd[4];
        #pragma unroll
        for (int r = 0; r < 4; r++) invd[r] = 1.0f / dk[mi][r];
        #pragma unroll
        for (int ni = 0; ni < 2; ni++) {
            int gc = n0 + nb + ni * 16 + qr;
            short4v st;
            #pragma unroll
            for (int r = 0; r < 4; r++)
                st[r] = f2bf(vvp[mi][ni][r] - acc[mi][ni][r] * invd[r]);
            *(short4v*)&uT[(size_t)gc * 4096 + gr0] = st;
        }
    }
}

// ---------------------------------------------------------------------------
// GEMM 4 (64x64, dbuf single-barrier): delta, split-K=8, accumulates
// directly into out_mem (pre-initialized to memory) via f32 atomics.
// ---------------------------------------------------------------------------
__global__ __launch_bounds__(256) void gemm_delta_mfma(
        const short* __restrict__ keluT, const short* __restrict__ uT,
        float* __restrict__ out_mem) {
    __shared__ __align__(16) short SMEM[16384];
    const int j0 = blockIdx.x * 64, i0 = blockIdx.y * 64;
    const int kcz = blockIdx.z;            // 0..7, K-chunk of 512
    const int tid = threadIdx.x, lane = tid & 63, wv = tid >> 6;
    const int qr = lane & 15, kg = lane >> 4;
    const int mb = (wv >> 1) * 32, nb = (wv & 1) * 32;

    f32x4 acc[2][2];
    #pragma unroll
    for (int i = 0; i < 2; i++)
        #pragma unroll
        for (int j = 0; j < 2; j++) acc[i][j] = (f32x4){0.f, 0.f, 0.f, 0.f};

    stage_gl64(keluT, 4096, i0, kcz * 512, SMEM, wv, lane);
    stage_gl64(uT, 4096, j0, kcz * 512, SMEM + 4096, wv, lane);
    for (int kt = 0; kt < 8; kt++) {
        const int cur = kt & 1;
        short* Acur = SMEM + cur * 8192;
        short* Bcur = Acur + 4096;
        __syncthreads();
        if (kt + 1 < 8) {
            int k0 = kcz * 512 + (kt + 1) * 64;
            short* Anxt = SMEM + (cur ^ 1) * 8192;
            stage_gl64(keluT, 4096, i0, k0, Anxt, wv, lane);
            stage_gl64(uT, 4096, j0, k0, Anxt + 4096, wv, lane);
        }
        mma_tile64(Acur, Bcur, mb, nb, qr, kg, acc);
    }

    #pragma unroll
    for (int mi = 0; mi < 2; mi++)
        #pragma unroll
        for (int ni = 0; ni < 2; ni++)
            #pragma unroll
            for (int r = 0; r < 4; r++) {
                int gr = i0 + mb + mi * 16 + kg * 4 + r;
                int gc = j0 + nb + ni * 16 + qr;
                atomicAdd(&out_mem[(size_t)gr * 512 + gc], acc[mi][ni][r]);
            }
}

// ---------------------------------------------------------------------------
// Flash attention (R17): XCD-grouped 1D dispatch; swapped QK^T, pre-scaled Q,
// global_load_lds K/V staging (double-buffered), NO-MAX exp2 softmax,
// l via ones-MFMA, P via per-wave LDS. Writes bf16 a_dot.
// ---------------------------------------------------------------------------
__global__ __launch_bounds__(256) void flash_attn_mfma(
        const short* __restrict__ qb, const short* __restrict__ kb,
        const short* __restrict__ vt, short* __restrict__ adotb) {
    __shared__ __align__(16) short Klds[2][4096];   // [t=64][d=64] swizzled
    __shared__ __align__(16) short Vlds[2][4096];   // [d=64][t=64] swizzled
    __shared__ __align__(16) short Plds[4096];      // 4 waves x [q=16][t=64]

    // XCD-grouped decode (bijective on 0..1023)
    const int id = blockIdx.x;
    const int low3 = id & 7, rest = id >> 3;
    const int xblk = rest & 31, bhhi = rest >> 5;
    const int bh = (bhhi << 3) | low3;
    const int r0 = xblk * 64;
    const int b = bh >> 4, qh = bh & 15;
    const int kvh = qh >> 1;
    const int tid = threadIdx.x;
    const int lane = tid & 63, wv = tid >> 6;
    const int qr = lane & 15, kg = lane >> 4;
    const float scale2 = 0.125f * 1.44269504f;   // 1/sqrt(64) * log2(e)

    const int srow = lane >> 3, sslot = lane & 7;

    // staging pointers, advanced per tile (hoisted address math)
    const int krow0 = wv * 16 + srow, krow1 = krow0 + 8;
    const short* kp0 = kb + (size_t)(b * SS + krow0) * KVD + kvh * DH
                       + (sslot ^ (krow0 & 7)) * 8;
    const short* kp1 = kb + (size_t)(b * SS + krow1) * KVD + kvh * DH
                       + (sslot ^ (krow1 & 7)) * 8;
    const short* vp0 = vt + ((size_t)(b * NH + kvh) * DH + krow0) * SS
                       + (sslot ^ (krow0 & 7)) * 8;
    const short* vp1 = vt + ((size_t)(b * NH + kvh) * DH + krow1) * SS
                       + (sslot ^ (krow1 & 7)) * 8;

    // Q fragments, pre-scaled by scale2 (one-time cost)
    short8 qa[2];
    {
        const short* qp = qb + (size_t)(b * SS + r0 + wv * 16 + qr) * DM + qh * DH;
        qa[0] = *(const short8*)&qp[kg * 8];
        qa[1] = *(const short8*)&qp[32 + kg * 8];
        #pragma unroll
        for (int e = 0; e < 8; e++) {
            qa[0][e] = f2bf(bf2f(qa[0][e]) * scale2);
            qa[1][e] = f2bf(bf2f(qa[1][e]) * scale2);
        }
    }
    short8 ones;
    #pragma unroll
    for (int e = 0; e < 8; e++) ones[e] = (short)0x3F80;   // bf16 1.0

    f32x4 oacc[4];
    #pragma unroll
    for (int dt = 0; dt < 4; dt++) oacc[dt] = (f32x4){0.f, 0.f, 0.f, 0.f};
    f32x4 lacc = (f32x4){0.f, 0.f, 0.f, 0.f};

    short* Pw = Plds + wv * 1024;
    short* Kdst0 = &Klds[0][(wv * 16 + 0) * 64];
    short* Kdst1 = &Klds[0][(wv * 16 + 8) * 64];
    short* Vdst0 = &Vlds[0][(wv * 16 + 0) * 64];
    short* Vdst1 = &Vlds[0][(wv * 16 + 8) * 64];

    // prologue: stage tile 0 into buffer 0
    GLD16(kp0, Kdst0); GLD16(kp1, Kdst1);
    GLD16(vp0, Vdst0); GLD16(vp1, Vdst1);

    for (int it = 0; it < 32; ++it) {
        const int cur = it & 1;
        __syncthreads();                 // drains DMA(it); all waves past it-1
        if (it + 1 < 32) {
            kp0 += 64 * KVD; kp1 += 64 * KVD; vp0 += 64; vp1 += 64;
            int nb2 = (cur ^ 1) * 4096;
            GLD16(kp0, Kdst0 + nb2); GLD16(kp1, Kdst1 + nb2);
            GLD16(vp0, Vdst0 + nb2); GLD16(vp1, Vdst1 + nb2);
        }

        // ---- S^T = mfma(K, Q): lane holds S[q=qr][key = j*16 + kg*4 + r] ----
        f32x4 sacc[4];
        #pragma unroll
        for (int j = 0; j < 4; j++) sacc[j] = (f32x4){0.f, 0.f, 0.f, 0.f};
        __builtin_amdgcn_s_setprio(1);
        #pragma unroll
        for (int c = 0; c < 2; c++) {
            #pragma unroll
            for (int j = 0; j < 4; j++) {
                short8 kf = *(const short8*)&Klds[cur][swzs(j * 16 + qr, kg * 16 + c * 64)];
                sacc[j] = __builtin_amdgcn_mfma_f32_16x16x32_bf16(kf, qa[c], sacc[j], 0, 0, 0);
            }
        }
        __builtin_amdgcn_s_setprio(0);

        // ---- no-max softmax: p = exp2(s) directly; P via cvt_pk + b64 store
        #pragma unroll
        for (int j = 0; j < 4; j++) {
            float p0 = exp2f(sacc[j][0]);
            float p1 = exp2f(sacc[j][1]);
            float p2 = exp2f(sacc[j][2]);
            float p3 = exp2f(sacc[j][3]);
            uint2v u;
            u[0] = cvtpk(p0, p1);
            u[1] = cvtpk(p2, p3);
            *(uint2v*)&Pw[swzs(qr, j * 32 + kg * 8)] = u;
        }
        asm volatile("s_waitcnt lgkmcnt(0)" ::: "memory");
        __builtin_amdgcn_sched_barrier(0);

        // ---- O^T += mfma(V^T, P^T); l += mfma(ones, P^T) ----
        __builtin_amdgcn_s_setprio(1);
        #pragma unroll
        for (int c = 0; c < 2; c++) {
            short8 pf = *(const short8*)&Pw[swzs(qr, kg * 16 + c * 64)];
            lacc = __builtin_amdgcn_mfma_f32_16x16x32_bf16(ones, pf, lacc, 0, 0, 0);
            #pragma unroll
            for (int dt = 0; dt < 4; dt++) {
                short8 vf = *(const short8*)&Vlds[cur][swzs(dt * 16 + qr, kg * 16 + c * 64)];
                oacc[dt] = __builtin_amdgcn_mfma_f32_16x16x32_bf16(vf, pf, oacc[dt], 0, 0, 0);
            }
        }
        __builtin_amdgcn_s_setprio(0);
    }

    // epilogue: l = lacc[0] (all entries/lanes identical); write bf16 a_dot
    float inv = 1.0f / lacc[0];
    short* ap = adotb + (size_t)(b * SS + r0 + wv * 16 + qr) * DM + qh * DH;
    #pragma unroll
    for (int dt = 0; dt < 4; dt++) {
        short4v st;
        #pragma unroll
        for (int r = 0; r < 4; r++) st[r] = f2bf(oacc[dt][r] * inv);
        *(short4v*)&ap[dt * 16 + kg * 4] = st;
    }
}

// ---------------------------------------------------------------------------
extern "C" void kernel_launch(void* const* d_in, const int* in_sizes, int n_in,
                              void* d_out, int out_size, void* d_ws, size_t ws_size,
                              hipStream_t stream) {
    const float* x      = (const float*)d_in[0];
    const float* Wq     = (const float*)d_in[1];
    const float* Wk     = (const float*)d_in[2];
    const float* Wv     = (const float*)d_in[3];
    const float* memory = (const float*)d_in[4];
    const float* mnorm  = (const float*)d_in[5];
    const float* mw     = (const float*)d_in[6];

    float* out_f   = (float*)d_out;                 // 4096x1024
    float* out_mem = out_f + (size_t)MROWS * DM;    // 512x512
    float* out_nrm = out_mem + (size_t)KVD * KVD;   // 512

    // Workspace (~52.6 MB).
    // adotb ALIASES xb (xb dead after gemm_qkv; adotb consumed by gemm_amem).
    short*  xb    = (short*)d_ws;                   // 4,194,304 shorts
    short*  wtb   = xb + 4194304;                   // 2,097,152
    short*  memtb = wtb + 2097152;                  // 262,144
    short*  qb    = memtb + 262144;                 // 4,194,304
    short*  kbuf  = qb + 4194304;                   // 2,097,152
    short*  vbuf  = kbuf + 2097152;                 // 2,097,152
    short*  vt    = vbuf + 2097152;                 // 2,097,152
    short*  qelu  = vt + 2097152;                   // 4,194,304
    short*  kelu  = qelu + 4194304;                 // 2,097,152
    short*  keluT = kelu + 2097152;                 // 2,097,152
    short*  uT    = keluT + 2097152;                // 2,097,152
    float*  den_q = (float*)(uT + 2097152);         // 8192
    float*  den_k = den_q + 8192;                   // 4096
    short*  adotb = xb;                             // alias (see above)

    prep_all<<<2880, 256, 0, stream>>>(x, Wq, Wk, Wv, memory, xb, wtb, memtb,
                                       out_mem);

    gemm_qkv_mfma<<<dim3(16, 32), 256, 0, stream>>>(xb, wtb, qb, kbuf, vbuf,
                                                    qelu, kelu, keluT, vt);

    flash_attn_mfma<<<1024, 256, 0, stream>>>(qb, kbuf, vt, adotb);

    den_colsum<<<3200, 256, 0, stream>>>(qelu, kelu, keluT, mnorm,
                                         den_q, den_k, out_nrm);

    gemm_amem_mfma<<<dim3(8, 128), 256, 0, stream>>>(qelu, memtb, adotb,
                                                     den_q, mw, out_f);

    gemm_u_mfma<<<dim3(8, 64), 256, 0, stream>>>(kelu, memtb, vbuf, den_k, uT);
    gemm_delta_mfma<<<dim3(8, 8, 8), 256, 0, stream>>>(keluT, uT, out_mem);
}

// Round 22
// 147.287 us; speedup vs baseline: 1.0068x; 1.0068x over previous
//
#include <hip/hip_runtime.h>
#include <hip/hip_bf16.h>

// Problem constants
#define BB 2
#define SS 2048
#define DM 1024
#define KVD 512
#define NH 8
#define NQ 2
#define QH 16
#define DH 64
#define MROWS 4096   // B*S

typedef float f32x4 __attribute__((ext_vector_type(4)));
typedef short short8 __attribute__((ext_vector_type(8)));
typedef short short4v __attribute__((ext_vector_type(4)));
typedef unsigned uint2v __attribute__((ext_vector_type(2)));

__device__ __forceinline__ float elu_f(float x) {
    return x > 0.0f ? x : (__expf(x) - 1.0f);
}

// float -> bf16 (round to nearest even), raw short
__device__ __forceinline__ short f2bf(float f) {
    union { float f; unsigned u; } v; v.f = f;
    unsigned r = v.u + 0x7FFFu + ((v.u >> 16) & 1u);
    return (short)(r >> 16);
}
__device__ __forceinline__ float bf2f(short s) {
    union { unsigned u; float f; } v;
    v.u = ((unsigned)(unsigned short)s) << 16;
    return v.f;
}
// packed f32x2 -> bf16x2 (hardware cvt)
__device__ __forceinline__ unsigned cvtpk(float lo, float hi) {
    unsigned u;
    asm("v_cvt_pk_bf16_f32 %0, %1, %2" : "=v"(u) : "v"(lo), "v"(hi));
    return u;
}

// XOR-swizzled LDS index (in shorts) for 128B rows: bijective 16B-slot permute.
__device__ __forceinline__ int swzs(int row, int byteoff) {
    return (row * 128 + (byteoff ^ ((row & 7) << 4))) >> 1;
}

// global -> LDS direct DMA, 16B per lane. LDS dest linear; source pre-swizzled.
#define GLD16(gp, lp) __builtin_amdgcn_global_load_lds( \
    (const __attribute__((address_space(1))) void*)(gp), \
    (__attribute__((address_space(3))) void*)(lp), 16, 0, 0)

// ---------------------------------------------------------------------------
// 128-row x 64-col staging (256 thr): LDS[r][s] = G[r][s ^ (r&7)]
// ---------------------------------------------------------------------------
__device__ __forceinline__ void stage_gl(const short* __restrict__ src, int ld,
                                         int row0, int k0, short* L,
                                         int wv, int lane) {
    const int srow = lane >> 3, sslot = lane & 7;
    #pragma unroll
    for (int i = 0; i < 4; i++) {
        int row = wv * 32 + i * 8 + srow;
        int slot = sslot ^ (row & 7);
        GLD16(&src[(size_t)(row0 + row) * ld + k0 + slot * 8],
              &L[(wv * 32 + i * 8) * 64]);
    }
}

// 64-row x 64-col staging (256 thr = 4 waves, 2 GLD16 each)
__device__ __forceinline__ void stage_gl64(const short* __restrict__ src, int ld,
                                           int row0, int k0, short* L,
                                           int wv, int lane) {
    const int srow = lane >> 3, sslot = lane & 7;
    #pragma unroll
    for (int i = 0; i < 2; i++) {
        int row = wv * 16 + i * 8 + srow;
        int slot = sslot ^ (row & 7);
        GLD16(&src[(size_t)(row0 + row) * ld + k0 + slot * 8],
              &L[(wv * 16 + i * 8) * 64]);
    }
}

__device__ __forceinline__ void mma_tile(const short* __restrict__ Als,
                                         const short* __restrict__ Bls,
                                         int mb, int nb, int qr, int kg,
                                         f32x4 acc[4][4]) {
    #pragma unroll
    for (int kc = 0; kc < 2; kc++) {
        short8 af[4], bg[4];
        #pragma unroll
        for (int mi = 0; mi < 4; mi++)
            af[mi] = *(const short8*)&Als[swzs(mb + mi * 16 + qr, kc * 64 + kg * 16)];
        #pragma unroll
        for (int ni = 0; ni < 4; ni++)
            bg[ni] = *(const short8*)&Bls[swzs(nb + ni * 16 + qr, kc * 64 + kg * 16)];
        #pragma unroll
        for (int mi = 0; mi < 4; mi++)
            #pragma unroll
            for (int ni = 0; ni < 4; ni++)
                acc[mi][ni] = __builtin_amdgcn_mfma_f32_16x16x32_bf16(
                    af[mi], bg[ni], acc[mi][ni], 0, 0, 0);
    }
}

// 64x64 tile: 4 waves in 2x2 grid, each 32x32 (2x2 fragments)
__device__ __forceinline__ void mma_tile64(const short* __restrict__ Als,
                                           const short* __restrict__ Bls,
                                           int mb, int nb, int qr, int kg,
                                           f32x4 acc[2][2]) {
    #pragma unroll
    for (int kc = 0; kc < 2; kc++) {
        short8 af[2], bg[2];
        #pragma unroll
        for (int mi = 0; mi < 2; mi++)
            af[mi] = *(const short8*)&Als[swzs(mb + mi * 16 + qr, kc * 64 + kg * 16)];
        #pragma unroll
        for (int ni = 0; ni < 2; ni++)
            bg[ni] = *(const short8*)&Bls[swzs(nb + ni * 16 + qr, kc * 64 + kg * 16)];
        #pragma unroll
        for (int mi = 0; mi < 2; mi++)
            #pragma unroll
            for (int ni = 0; ni < 2; ni++)
                acc[mi][ni] = __builtin_amdgcn_mfma_f32_16x16x32_bf16(
                    af[mi], bg[ni], acc[mi][ni], 0, 0, 0);
    }
}

// ---------------------------------------------------------------------------
// Fused prep: [0,2048) convert_x | [2048,2560) transpose_w | [2560,2624) mem
//             [2624,2880) out_mem = memory (delta GEMM accumulates via atomics)
// ---------------------------------------------------------------------------
__global__ __launch_bounds__(256) void prep_all(
        const float* __restrict__ x, const float* __restrict__ Wq,
        const float* __restrict__ Wk, const float* __restrict__ Wv,
        const float* __restrict__ memory,
        short* __restrict__ xb, short* __restrict__ wtb,
        short* __restrict__ memtb, float* __restrict__ out_mem) {
    __shared__ float Ts[64][65];
    const int blk = blockIdx.x;
    const int tid = threadIdx.x;

    if (blk < 2048) {                      // convert x -> bf16
        int i = (blk * 256 + tid) * 8;
        float4 a = *(const float4*)&x[i];
        float4 b = *(const float4*)&x[i + 4];
        short8 s;
        s[0] = f2bf(a.x); s[1] = f2bf(a.y); s[2] = f2bf(a.z); s[3] = f2bf(a.w);
        s[4] = f2bf(b.x); s[5] = f2bf(b.y); s[6] = f2bf(b.z); s[7] = f2bf(b.w);
        *(short8*)&xb[i] = s;
        return;
    }
    if (blk < 2560) {                      // Wt[n][k] = W[k][n] (fused q|k|v)
        int idx = blk - 2048;
        const int k0 = (idx & 15) * 64, n0 = (idx >> 4) * 64;
        const float* W; int ld, c0;
        if (n0 < 1024)      { W = Wq; ld = 1024; c0 = n0; }
        else if (n0 < 1536) { W = Wk; ld = 512;  c0 = n0 - 1024; }
        else                { W = Wv; ld = 512;  c0 = n0 - 1536; }
        #pragma unroll
        for (int i = 0; i < 16; i++) {
            int e = tid + 256 * i;
            int kk = e >> 6, nn = e & 63;
            Ts[nn][kk] = W[(size_t)(k0 + kk) * ld + c0 + nn];
        }
        __syncthreads();
        #pragma unroll
        for (int i = 0; i < 16; i++) {
            int e = tid + 256 * i;
            int nn = e >> 6, kk = e & 63;
            wtb[(size_t)(n0 + nn) * 1024 + k0 + kk] = f2bf(Ts[nn][kk]);
        }
        return;
    }
    if (blk < 2624) {                      // memT[n][k] = memory[k][n]
        int idx = blk - 2560;
        const int k0 = (idx & 7) * 64, n0 = (idx >> 3) * 64;
        #pragma unroll
        for (int i = 0; i < 16; i++) {
            int e = tid + 256 * i;
            int kk = e >> 6, nn = e & 63;
            Ts[nn][kk] = memory[(size_t)(k0 + kk) * 512 + n0 + nn];
        }
        __syncthreads();
        #pragma unroll
        for (int i = 0; i < 16; i++) {
            int e = tid + 256 * i;
            int nn = e >> 6, kk = e & 63;
            memtb[(size_t)(n0 + nn) * 512 + k0 + kk] = f2bf(Ts[nn][kk]);
        }
        return;
    }
    {                                      // out_mem = memory (float4)
        int idx = blk - 2624;              // 0..255
        int i = (idx * 256 + tid) * 4;
        *(float4*)&out_mem[i] = *(const float4*)&memory[i];
    }
}

// ---------------------------------------------------------------------------
// GEMM 1: QKV, 128x128 tiles, single-barrier double-buffered K-loop.
// Q -> qb,qelu ; K -> kbuf,kelu,keluT ; V -> vbuf,vt
// Tls ALIASES buffers (dead after K-loop; explicit barrier before reuse).
// ---------------------------------------------------------------------------
__global__ __launch_bounds__(256) void gemm_qkv_mfma(
        const short* __restrict__ xb, const short* __restrict__ wtb,
        short* __restrict__ q, short* __restrict__ k, short* __restrict__ v,
        short* __restrict__ qelu, short* __restrict__ kelu,
        short* __restrict__ keluT, short* __restrict__ vt) {
    __shared__ __align__(16) short SMEM[32768];   // A0 B0 A1 B1 (4x8192); Tls aliases
    short (*Tls)[130] = (short(*)[130])SMEM;
    const int n0 = blockIdx.x * 128, m0 = blockIdx.y * 128;
    const int tid = threadIdx.x, lane = tid & 63, wv = tid >> 6;
    const int qr = lane & 15, kg = lane >> 4;
    const int mb = (wv >> 1) * 64, nb = (wv & 1) * 64;

    f32x4 acc[4][4];
    #pragma unroll
    for (int i = 0; i < 4; i++)
        #pragma unroll
        for (int j = 0; j < 4; j++) acc[i][j] = (f32x4){0.f, 0.f, 0.f, 0.f};

    // prologue: stage tile 0 into buffer set 0
    stage_gl(xb, 1024, m0, 0, SMEM, wv, lane);
    stage_gl(wtb, 1024, n0, 0, SMEM + 8192, wv, lane);

    for (int kt = 0; kt < 16; kt++) {
        const int cur = kt & 1;
        short* Acur = SMEM + cur * 16384;
        short* Bcur = Acur + 8192;
        __syncthreads();               // drains DMA for tile kt
        if (kt + 1 < 16) {
            short* Anxt = SMEM + (cur ^ 1) * 16384;
            stage_gl(xb, 1024, m0, (kt + 1) * 64, Anxt, wv, lane);
            stage_gl(wtb, 1024, n0, (kt + 1) * 64, Anxt + 8192, wv, lane);
        }
        mma_tile(Acur, Bcur, mb, nb, qr, kg, acc);
    }
    __syncthreads();   // all waves done with buffers before Tls overwrite

    const int kind = (n0 < 1024) ? 0 : (n0 < 1536) ? 1 : 2;
    #pragma unroll
    for (int mi = 0; mi < 4; mi++)
        #pragma unroll
        for (int ni = 0; ni < 4; ni++)
            #pragma unroll
            for (int r = 0; r < 4; r++) {
                int lr = mb + mi * 16 + kg * 4 + r;
                int lc = nb + ni * 16 + qr;
                int gr = m0 + lr;
                short val = f2bf(acc[mi][ni][r]);
                if (kind == 0) {
                    int gc = n0 + lc;
                    q[(size_t)gr * 1024 + gc] = val;
                    qelu[(size_t)gr * 1024 + gc] = f2bf(elu_f(bf2f(val)));
                } else if (kind == 1) {
                    int gc = (n0 - 1024) + lc;
                    k[(size_t)gr * 512 + gc] = val;
                    short ev = f2bf(elu_f(bf2f(val)));
                    kelu[(size_t)gr * 512 + gc] = ev;
                    Tls[lr][lc] = ev;
                } else {
                    int gc = (n0 - 1536) + lc;
                    v[(size_t)gr * 512 + gc] = val;
                    Tls[lr][lc] = val;
                }
            }

    if (kind == 0) return;
    __syncthreads();
    // transposed coalesced writes: out-row = local col, 128 contiguous elems
    const int lane16 = tid & 15, rgrp = tid >> 4;   // 16 row-groups of 16 lanes
    #pragma unroll
    for (int p = 0; p < 8; p++) {
        int lc2 = p * 16 + rgrp;
        short8 s;
        #pragma unroll
        for (int e = 0; e < 8; e++) s[e] = Tls[lane16 * 8 + e][lc2];
        if (kind == 1) {
            int gcT = (n0 - 1024) + lc2;
            *(short8*)&keluT[(size_t)gcT * 4096 + m0 + lane16 * 8] = s;
        } else {
            int gc = (n0 - 1536) + lc2;
            int bh2 = (m0 >> 11) * 8 + (gc >> 6);
            *(short8*)&vt[((size_t)bh2 * 64 + (gc & 63)) * SS + (m0 & 2047)
                          + lane16 * 8] = s;
        }
    }
}

// ---------------------------------------------------------------------------
// dens (blocks 0..3071: 12288 rows) + colsum of keluT (blocks 3072..3199)
// ---------------------------------------------------------------------------
__global__ __launch_bounds__(256) void den_colsum(
        const short* __restrict__ qelu, const short* __restrict__ kelu,
        const short* __restrict__ keluT, const float* __restrict__ norm,
        float* __restrict__ den_q, float* __restrict__ den_k,
        float* __restrict__ out_norm) {
    const int wavei = threadIdx.x >> 6, lane = threadIdx.x & 63;
    const int blk = blockIdx.x;
    if (blk < 3072) {
        const int row = blk * 4 + wavei;    // 12288 rows
        const short* src; float* den;
        if (row < 8192) { src = qelu + (size_t)row * 512; den = den_q + row; }
        else { int rk = row - 8192; src = kelu + (size_t)rk * 512; den = den_k + rk; }
        short8 vv = *(const short8*)&src[lane * 8];
        float4 n0 = *(const float4*)&norm[lane * 8];
        float4 n1 = *(const float4*)&norm[lane * 8 + 4];
        float nn[8] = {n0.x, n0.y, n0.z, n0.w, n1.x, n1.y, n1.z, n1.w};
        float s = 0.0f;
        #pragma unroll
        for (int j = 0; j < 8; j++) s += bf2f(vv[j]) * nn[j];
        #pragma unroll
        for (int off = 32; off >= 1; off >>= 1) s += __shfl_xor(s, off);
        if (lane == 0) *den = s;
    } else {
        const int row = (blk - 3072) * 4 + wavei;   // 512 rows of keluT
        float s = 0.0f;
        #pragma unroll
        for (int j = 0; j < 8; j++) {
            short8 vv = *(const short8*)&keluT[(size_t)row * 4096 + j * 512 + lane * 8];
            #pragma unroll
            for (int e = 0; e < 8; e++) s += bf2f(vv[e]);
        }
        #pragma unroll
        for (int off = 32; off >= 1; off >>= 1) s += __shfl_xor(s, off);
        if (lane == 0) out_norm[row] = norm[row] + s;
    }
}

// ---------------------------------------------------------------------------
// GEMM 2 (64x64, dbuf single-barrier): a_mem + blend -> out
// ---------------------------------------------------------------------------
__global__ __launch_bounds__(256) void gemm_amem_mfma(
        const short* __restrict__ qelu, const short* __restrict__ memtb,
        const short* __restrict__ adotb, const float* __restrict__ den_q,
        const float* __restrict__ mw, float* __restrict__ out) {
    __shared__ __align__(16) short SMEM[16384];   // A0 B0 A1 B1 (4x4096)
    const int n0 = blockIdx.x * 64, m0 = blockIdx.y * 64;
    const int tid = threadIdx.x, lane = tid & 63, wv = tid >> 6;
    const int qr = lane & 15, kg = lane >> 4;
    const int mb = (wv >> 1) * 32, nb = (wv & 1) * 32;
    const float wgt = 1.0f / (1.0f + __expf(-mw[0]));

    f32x4 acc[2][2];
    #pragma unroll
    for (int i = 0; i < 2; i++)
        #pragma unroll
        for (int j = 0; j < 2; j++) acc[i][j] = (f32x4){0.f, 0.f, 0.f, 0.f};

    stage_gl64(qelu, 512, m0, 0, SMEM, wv, lane);
    stage_gl64(memtb, 512, n0, 0, SMEM + 4096, wv, lane);
    for (int kt = 0; kt < 8; kt++) {
        const int cur = kt & 1;
        short* Acur = SMEM + cur * 8192;
        short* Bcur = Acur + 4096;
        __syncthreads();
        if (kt + 1 < 8) {
            short* Anxt = SMEM + (cur ^ 1) * 8192;
            stage_gl64(qelu, 512, m0, (kt + 1) * 64, Anxt, wv, lane);
            stage_gl64(memtb, 512, n0, (kt + 1) * 64, Anxt + 4096, wv, lane);
        }
        mma_tile64(Acur, Bcur, mb, nb, qr, kg, acc);
    }

    #pragma unroll
    for (int mi = 0; mi < 2; mi++) {
        int gr0 = m0 + mb + mi * 16 + kg * 4;
        float invd[4];
        #pragma unroll
        for (int r = 0; r < 4; r++) invd[r] = wgt / den_q[gr0 + r];
        #pragma unroll
        for (int ni = 0; ni < 2; ni++) {
            int gc = n0 + nb + ni * 16 + qr;
            #pragma unroll
            for (int r = 0; r < 4; r++) {
                size_t fo = (size_t)(gr0 + r) * 512 + gc;
                out[fo] = bf2f(adotb[fo]) * (1.0f - wgt)
                        + acc[mi][ni][r] * invd[r];
            }
        }
    }
}

// ---------------------------------------------------------------------------
// GEMM 3 (64x64, dbuf single-barrier): u = v - (kelu@memory)/den_k -> uT bf16
// ---------------------------------------------------------------------------
__global__ __launch_bounds__(256) void gemm_u_mfma(
        const short* __restrict__ kelu, const short* __restrict__ memtb,
        const short* __restrict__ vb, const float* __restrict__ den_k,
        short* __restrict__ uT) {
    __shared__ __align__(16) short SMEM[16384];
    const int n0 = blockIdx.x * 64, m0 = blockIdx.y * 64;
    const int tid = threadIdx.x, lane = tid & 63, wv = tid >> 6;
    const int qr = lane & 15, kg = lane >> 4;
    const int mb = (wv >> 1) * 32, nb = (wv & 1) * 32;

    f32x4 acc[2][2];
    #pragma unroll
    for (int i = 0; i < 2; i++)
        #pragma unroll
        for (int j = 0; j < 2; j++) acc[i][j] = (f32x4){0.f, 0.f, 0.f, 0.f};

    stage_gl64(kelu, 512, m0, 0, SMEM, wv, lane);
    stage_gl64(memtb, 512, n0, 0, SMEM + 4096, wv, lane);
    for (int kt = 0; kt < 8; kt++) {
        const int cur = kt & 1;
        short* Acur = SMEM + cur * 8192;
        short* Bcur = Acur + 4096;
        __syncthreads();
        if (kt + 1 < 8) {
            short* Anxt = SMEM + (cur ^ 1) * 8192;
            stage_gl64(kelu, 512, m0, (kt + 1) * 64, Anxt, wv, lane);
            stage_gl64(memtb, 512, n0, (kt + 1) * 64, Anxt + 4096, wv, lane);
        }
        mma_tile64(Acur, Bcur, mb, nb, qr, kg, acc);
    }

    #pragma unroll
    for (int mi = 0; mi < 2; mi++) {
        int gr0 = m0 + mb + mi * 16 + kg * 4;
        float invd[4];
        #pragma unroll
        for (int r = 0; r < 4; r++) invd[r] = 1.0f / den_k[gr0 + r];
        #pragma unroll
        for (int ni = 0; ni < 2; ni++) {
            int gc = n0 + nb + ni * 16 + qr;
            short4v st;
            #pragma unroll
            for (int r = 0; r < 4; r++)
                st[r] = f2bf(bf2f(vb[(size_t)(gr0 + r) * 512 + gc])
                             - acc[mi][ni][r] * invd[r]);
            *(short4v*)&uT[(size_t)gc * 4096 + gr0] = st;
        }
    }
}

// ---------------------------------------------------------------------------
// GEMM 4 (64x64, dbuf single-barrier): delta, split-K=8, accumulates
// directly into out_mem (pre-initialized to memory) via f32 atomics.
// ---------------------------------------------------------------------------
__global__ __launch_bounds__(256) void gemm_delta_mfma(
        const short* __restrict__ keluT, const short* __restrict__ uT,
        float* __restrict__ out_mem) {
    __shared__ __align__(16) short SMEM[16384];
    const int j0 = blockIdx.x * 64, i0 = blockIdx.y * 64;
    const int kcz = blockIdx.z;            // 0..7, K-chunk of 512
    const int tid = threadIdx.x, lane = tid & 63, wv = tid >> 6;
    const int qr = lane & 15, kg = lane >> 4;
    const int mb = (wv >> 1) * 32, nb = (wv & 1) * 32;

    f32x4 acc[2][2];
    #pragma unroll
    for (int i = 0; i < 2; i++)
        #pragma unroll
        for (int j = 0; j < 2; j++) acc[i][j] = (f32x4){0.f, 0.f, 0.f, 0.f};

    stage_gl64(keluT, 4096, i0, kcz * 512, SMEM, wv, lane);
    stage_gl64(uT, 4096, j0, kcz * 512, SMEM + 4096, wv, lane);
    for (int kt = 0; kt < 8; kt++) {
        const int cur = kt & 1;
        short* Acur = SMEM + cur * 8192;
        short* Bcur = Acur + 4096;
        __syncthreads();
        if (kt + 1 < 8) {
            int k0 = kcz * 512 + (kt + 1) * 64;
            short* Anxt = SMEM + (cur ^ 1) * 8192;
            stage_gl64(keluT, 4096, i0, k0, Anxt, wv, lane);
            stage_gl64(uT, 4096, j0, k0, Anxt + 4096, wv, lane);
        }
        mma_tile64(Acur, Bcur, mb, nb, qr, kg, acc);
    }

    #pragma unroll
    for (int mi = 0; mi < 2; mi++)
        #pragma unroll
        for (int ni = 0; ni < 2; ni++)
            #pragma unroll
            for (int r = 0; r < 4; r++) {
                int gr = i0 + mb + mi * 16 + kg * 4 + r;
                int gc = j0 + nb + ni * 16 + qr;
                atomicAdd(&out_mem[(size_t)gr * 512 + gc], acc[mi][ni][r]);
            }
}

// ---------------------------------------------------------------------------
// Flash attention (R17): XCD-grouped 1D dispatch; swapped QK^T, pre-scaled Q,
// global_load_lds K/V staging (double-buffered), NO-MAX exp2 softmax,
// l via ones-MFMA, P via per-wave LDS. Writes bf16 a_dot.
// ---------------------------------------------------------------------------
__global__ __launch_bounds__(256) void flash_attn_mfma(
        const short* __restrict__ qb, const short* __restrict__ kb,
        const short* __restrict__ vt, short* __restrict__ adotb) {
    __shared__ __align__(16) short Klds[2][4096];   // [t=64][d=64] swizzled
    __shared__ __align__(16) short Vlds[2][4096];   // [d=64][t=64] swizzled
    __shared__ __align__(16) short Plds[4096];      // 4 waves x [q=16][t=64]

    // XCD-grouped decode (bijective on 0..1023)
    const int id = blockIdx.x;
    const int low3 = id & 7, rest = id >> 3;
    const int xblk = rest & 31, bhhi = rest >> 5;
    const int bh = (bhhi << 3) | low3;
    const int r0 = xblk * 64;
    const int b = bh >> 4, qh = bh & 15;
    const int kvh = qh >> 1;
    const int tid = threadIdx.x;
    const int lane = tid & 63, wv = tid >> 6;
    const int qr = lane & 15, kg = lane >> 4;
    const float scale2 = 0.125f * 1.44269504f;   // 1/sqrt(64) * log2(e)

    const int srow = lane >> 3, sslot = lane & 7;

    // staging pointers, advanced per tile (hoisted address math)
    const int krow0 = wv * 16 + srow, krow1 = krow0 + 8;
    const short* kp0 = kb + (size_t)(b * SS + krow0) * KVD + kvh * DH
                       + (sslot ^ (krow0 & 7)) * 8;
    const short* kp1 = kb + (size_t)(b * SS + krow1) * KVD + kvh * DH
                       + (sslot ^ (krow1 & 7)) * 8;
    const short* vp0 = vt + ((size_t)(b * NH + kvh) * DH + krow0) * SS
                       + (sslot ^ (krow0 & 7)) * 8;
    const short* vp1 = vt + ((size_t)(b * NH + kvh) * DH + krow1) * SS
                       + (sslot ^ (krow1 & 7)) * 8;

    // Q fragments, pre-scaled by scale2 (one-time cost)
    short8 qa[2];
    {
        const short* qp = qb + (size_t)(b * SS + r0 + wv * 16 + qr) * DM + qh * DH;
        qa[0] = *(const short8*)&qp[kg * 8];
        qa[1] = *(const short8*)&qp[32 + kg * 8];
        #pragma unroll
        for (int e = 0; e < 8; e++) {
            qa[0][e] = f2bf(bf2f(qa[0][e]) * scale2);
            qa[1][e] = f2bf(bf2f(qa[1][e]) * scale2);
        }
    }
    short8 ones;
    #pragma unroll
    for (int e = 0; e < 8; e++) ones[e] = (short)0x3F80;   // bf16 1.0

    f32x4 oacc[4];
    #pragma unroll
    for (int dt = 0; dt < 4; dt++) oacc[dt] = (f32x4){0.f, 0.f, 0.f, 0.f};
    f32x4 lacc = (f32x4){0.f, 0.f, 0.f, 0.f};

    short* Pw = Plds + wv * 1024;
    short* Kdst0 = &Klds[0][(wv * 16 + 0) * 64];
    short* Kdst1 = &Klds[0][(wv * 16 + 8) * 64];
    short* Vdst0 = &Vlds[0][(wv * 16 + 0) * 64];
    short* Vdst1 = &Vlds[0][(wv * 16 + 8) * 64];

    // prologue: stage tile 0 into buffer 0
    GLD16(kp0, Kdst0); GLD16(kp1, Kdst1);
    GLD16(vp0, Vdst0); GLD16(vp1, Vdst1);

    for (int it = 0; it < 32; ++it) {
        const int cur = it & 1;
        __syncthreads();                 // drains DMA(it); all waves past it-1
        if (it + 1 < 32) {
            kp0 += 64 * KVD; kp1 += 64 * KVD; vp0 += 64; vp1 += 64;
            int nb2 = (cur ^ 1) * 4096;
            GLD16(kp0, Kdst0 + nb2); GLD16(kp1, Kdst1 + nb2);
            GLD16(vp0, Vdst0 + nb2); GLD16(vp1, Vdst1 + nb2);
        }

        // ---- S^T = mfma(K, Q): lane holds S[q=qr][key = j*16 + kg*4 + r] ----
        f32x4 sacc[4];
        #pragma unroll
        for (int j = 0; j < 4; j++) sacc[j] = (f32x4){0.f, 0.f, 0.f, 0.f};
        __builtin_amdgcn_s_setprio(1);
        #pragma unroll
        for (int c = 0; c < 2; c++) {
            #pragma unroll
            for (int j = 0; j < 4; j++) {
                short8 kf = *(const short8*)&Klds[cur][swzs(j * 16 + qr, kg * 16 + c * 64)];
                sacc[j] = __builtin_amdgcn_mfma_f32_16x16x32_bf16(kf, qa[c], sacc[j], 0, 0, 0);
            }
        }
        __builtin_amdgcn_s_setprio(0);

        // ---- no-max softmax: p = exp2(s) directly; P via cvt_pk + b64 store
        #pragma unroll
        for (int j = 0; j < 4; j++) {
            float p0 = exp2f(sacc[j][0]);
            float p1 = exp2f(sacc[j][1]);
            float p2 = exp2f(sacc[j][2]);
            float p3 = exp2f(sacc[j][3]);
            uint2v u;
            u[0] = cvtpk(p0, p1);
            u[1] = cvtpk(p2, p3);
            *(uint2v*)&Pw[swzs(qr, j * 32 + kg * 8)] = u;
        }
        asm volatile("s_waitcnt lgkmcnt(0)" ::: "memory");
        __builtin_amdgcn_sched_barrier(0);

        // ---- O^T += mfma(V^T, P^T); l += mfma(ones, P^T) ----
        __builtin_amdgcn_s_setprio(1);
        #pragma unroll
        for (int c = 0; c < 2; c++) {
            short8 pf = *(const short8*)&Pw[swzs(qr, kg * 16 + c * 64)];
            lacc = __builtin_amdgcn_mfma_f32_16x16x32_bf16(ones, pf, lacc, 0, 0, 0);
            #pragma unroll
            for (int dt = 0; dt < 4; dt++) {
                short8 vf = *(const short8*)&Vlds[cur][swzs(dt * 16 + qr, kg * 16 + c * 64)];
                oacc[dt] = __builtin_amdgcn_mfma_f32_16x16x32_bf16(vf, pf, oacc[dt], 0, 0, 0);
            }
        }
        __builtin_amdgcn_s_setprio(0);
    }

    // epilogue: l = lacc[0] (all entries/lanes identical); write bf16 a_dot
    float inv = 1.0f / lacc[0];
    short* ap = adotb + (size_t)(b * SS + r0 + wv * 16 + qr) * DM + qh * DH;
    #pragma unroll
    for (int dt = 0; dt < 4; dt++) {
        short4v st;
        #pragma unroll
        for (int r = 0; r < 4; r++) st[r] = f2bf(oacc[dt][r] * inv);
        *(short4v*)&ap[dt * 16 + kg * 4] = st;
    }
}

// ---------------------------------------------------------------------------
extern "C" void kernel_launch(void* const* d_in, const int* in_sizes, int n_in,
                              void* d_out, int out_size, void* d_ws, size_t ws_size,
                              hipStream_t stream) {
    const float* x      = (const float*)d_in[0];
    const float* Wq     = (const float*)d_in[1];
    const float* Wk     = (const float*)d_in[2];
    const float* Wv     = (const float*)d_in[3];
    const float* memory = (const float*)d_in[4];
    const float* mnorm  = (const float*)d_in[5];
    const float* mw     = (const float*)d_in[6];

    float* out_f   = (float*)d_out;                 // 4096x1024
    float* out_mem = out_f + (size_t)MROWS * DM;    // 512x512
    float* out_nrm = out_mem + (size_t)KVD * KVD;   // 512

    // Workspace (~52.6 MB).
    // adotb ALIASES xb (xb dead after gemm_qkv; adotb consumed by gemm_amem).
    short*  xb    = (short*)d_ws;                   // 4,194,304 shorts
    short*  wtb   = xb + 4194304;                   // 2,097,152
    short*  memtb = wtb + 2097152;                  // 262,144
    short*  qb    = memtb + 262144;                 // 4,194,304
    short*  kbuf  = qb + 4194304;                   // 2,097,152
    short*  vbuf  = kbuf + 2097152;                 // 2,097,152
    short*  vt    = vbuf + 2097152;                 // 2,097,152
    short*  qelu  = vt + 2097152;                   // 4,194,304
    short*  kelu  = qelu + 4194304;                 // 2,097,152
    short*  keluT = kelu + 2097152;                 // 2,097,152
    short*  uT    = keluT + 2097152;                // 2,097,152
    float*  den_q = (float*)(uT + 2097152);         // 8192
    float*  den_k = den_q + 8192;                   // 4096
    short*  adotb = xb;                             // alias (see above)

    prep_all<<<2880, 256, 0, stream>>>(x, Wq, Wk, Wv, memory, xb, wtb, memtb,
                                       out_mem);

    gemm_qkv_mfma<<<dim3(16, 32), 256, 0, stream>>>(xb, wtb, qb, kbuf, vbuf,
                                                    qelu, kelu, keluT, vt);

    flash_attn_mfma<<<1024, 256, 0, stream>>>(qb, kbuf, vt, adotb);

    den_colsum<<<3200, 256, 0, stream>>>(qelu, kelu, keluT, mnorm,
                                         den_q, den_k, out_nrm);

    gemm_amem_mfma<<<dim3(8, 128), 256, 0, stream>>>(qelu, memtb, adotb,
                                                     den_q, mw, out_f);

    gemm_u_mfma<<<dim3(8, 64), 256, 0, stream>>>(kelu, memtb, vbuf, den_k, uT);
    gemm_delta_mfma<<<dim3(8, 8, 8), 256, 0, stream>>>(keluT, uT, out_mem);
}